// Round 2
// baseline (1651.768 us; speedup 1.0000x reference)
//
#include <hip/hip_runtime.h>
#include <math.h>

#define B_ 128
#define D_ 4096
#define V_ 32000

// ---------------- threefry2x32, key = (0, 42), JAX-compatible ----------------
__device__ __forceinline__ void threefry2x32_0_42(unsigned& x0, unsigned& x1) {
  const unsigned k0 = 0u;
  const unsigned k1 = 42u;
  const unsigned k2 = 0u ^ 42u ^ 0x1BD11BDAu;
  x0 += k0; x1 += k1;
#define TF_R(r) { x0 += x1; x1 = (x1 << (r)) | (x1 >> (32 - (r))); x1 ^= x0; }
#define TF_G0 TF_R(13) TF_R(15) TF_R(26) TF_R(6)
#define TF_G1 TF_R(17) TF_R(29) TF_R(16) TF_R(24)
  TF_G0; x0 += k1; x1 += k2 + 1u;
  TF_G1; x0 += k2; x1 += k0 + 2u;
  TF_G0; x0 += k0; x1 += k1 + 3u;
  TF_G1; x0 += k1; x1 += k2 + 4u;
  TF_G0; x0 += k2; x1 += k0 + 5u;
#undef TF_G1
#undef TF_G0
#undef TF_R
}

// JAX gumbel from raw bits: u = max(tiny, mantissa_float); g = -log(-log(u))
__device__ __forceinline__ float gumbel_from_bits(unsigned bits) {
  float f = __uint_as_float((bits >> 9) | 0x3F800000u) - 1.0f;
  float u = fmaxf(f, 1.17549435e-38f);
  return -logf(-logf(u));
}

// ---------------- kernel 1: fp32 GEMM  L[b][v] = (A[b,:] . W[v,:]) / temp[b] --
// tile: 128 b x 64 v per block, BK=64, 256 threads, 8b x 4v per thread
__global__ __launch_bounds__(256) void gemm_kernel(
    const float* __restrict__ A, const float* __restrict__ W,
    const float* __restrict__ temp, float* __restrict__ L) {
  __shared__ float As[64 * 132];  // As[k][b], pad 132 keeps float4 reads aligned
  __shared__ float Ws[64 * 68];   // Ws[k][v]
  const int tid = threadIdx.x;
  const int vblock = blockIdx.x * 64;
  const int tv = tid & 15;   // v_local = tv*4
  const int tb = tid >> 4;   // b_local = tb*8

  float acc[8][4];
#pragma unroll
  for (int i = 0; i < 8; i++)
#pragma unroll
    for (int j = 0; j < 4; j++) acc[i][j] = 0.f;

  for (int k0 = 0; k0 < D_; k0 += 64) {
    __syncthreads();
    // stage A tile (128 x 64) transposed into As[k][b]
#pragma unroll
    for (int i = 0; i < 8; i++) {
      int f4 = tid + i * 256;          // 0..2047
      int b = f4 >> 4;
      int k4 = (f4 & 15) << 2;
      const float4 a = *reinterpret_cast<const float4*>(&A[(size_t)b * D_ + k0 + k4]);
      As[(k4 + 0) * 132 + b] = a.x;
      As[(k4 + 1) * 132 + b] = a.y;
      As[(k4 + 2) * 132 + b] = a.z;
      As[(k4 + 3) * 132 + b] = a.w;
    }
    // stage W tile (64 x 64) transposed into Ws[k][v]
#pragma unroll
    for (int i = 0; i < 4; i++) {
      int f4 = tid + i * 256;          // 0..1023
      int v = f4 >> 4;
      int k4 = (f4 & 15) << 2;
      const float4 w = *reinterpret_cast<const float4*>(&W[(size_t)(vblock + v) * D_ + k0 + k4]);
      Ws[(k4 + 0) * 68 + v] = w.x;
      Ws[(k4 + 1) * 68 + v] = w.y;
      Ws[(k4 + 2) * 68 + v] = w.z;
      Ws[(k4 + 3) * 68 + v] = w.w;
    }
    __syncthreads();
#pragma unroll 4
    for (int k = 0; k < 64; k++) {
      const float4 wv = *reinterpret_cast<const float4*>(&Ws[k * 68 + tv * 4]);
      const float4 a0 = *reinterpret_cast<const float4*>(&As[k * 132 + tb * 8]);
      const float4 a1 = *reinterpret_cast<const float4*>(&As[k * 132 + tb * 8 + 4]);
      const float av[8] = {a0.x, a0.y, a0.z, a0.w, a1.x, a1.y, a1.z, a1.w};
#pragma unroll
      for (int i = 0; i < 8; i++) {
        acc[i][0] = fmaf(av[i], wv.x, acc[i][0]);
        acc[i][1] = fmaf(av[i], wv.y, acc[i][1]);
        acc[i][2] = fmaf(av[i], wv.z, acc[i][2]);
        acc[i][3] = fmaf(av[i], wv.w, acc[i][3]);
      }
    }
  }
#pragma unroll
  for (int i = 0; i < 8; i++) {
    const int b = tb * 8 + i;
    const float t = temp[b];
    float4 r;
    r.x = acc[i][0] / t;
    r.y = acc[i][1] / t;
    r.z = acc[i][2] / t;
    r.w = acc[i][3] / t;
    *reinterpret_cast<float4*>(&L[(size_t)b * V_ + vblock + tv * 4]) = r;
  }
}

// ---------------- block reduction helpers (256 threads = 4 waves) -----------
__device__ __forceinline__ float blockMax256(float x, float* red) {
#pragma unroll
  for (int o = 32; o > 0; o >>= 1) x = fmaxf(x, __shfl_down(x, o));
  const int w = threadIdx.x >> 6;
  if ((threadIdx.x & 63) == 0) red[w] = x;
  __syncthreads();
  const float r = fmaxf(fmaxf(red[0], red[1]), fmaxf(red[2], red[3]));
  __syncthreads();
  return r;
}

__device__ __forceinline__ float blockSum256(float x, float* red) {
#pragma unroll
  for (int o = 32; o > 0; o >>= 1) x += __shfl_down(x, o);
  const int w = threadIdx.x >> 6;
  if ((threadIdx.x & 63) == 0) red[w] = x;
  __syncthreads();
  const float r = ((red[0] + red[1]) + red[2]) + red[3];
  __syncthreads();
  return r;
}

// ---------------- kernel 2: per-row top-p cutoff --------------------------
// kept(v) <=> F(e_v) = sum_{e_u > e_v} e_u <= top_p * S.  F monotone => binary
// search minimal kept e-bits; emit lmin = min logit among kept tokens.
__global__ __launch_bounds__(256) void topp_kernel(
    const float* __restrict__ L, const float* __restrict__ top_p,
    float* __restrict__ E, float* __restrict__ lmin_out, int use_e) {
  __shared__ float red[4];
  const int b = blockIdx.x;
  const int tid = threadIdx.x;
  const float* l = L + (size_t)b * V_;
  float* e = E + (size_t)b * V_;

  // pass 1: row max
  float m = -INFINITY;
  for (int v = tid; v < V_; v += 256) m = fmaxf(m, l[v]);
  m = blockMax256(m, red);

  // pass 2: e = exp(l - m), sum
  float s = 0.f;
  if (use_e) {
    for (int v = tid; v < V_; v += 256) {
      const float ev = expf(l[v] - m);
      e[v] = ev;
      s += ev;
    }
  } else {
    for (int v = tid; v < V_; v += 256) s += expf(l[v] - m);
  }
  s = blockSum256(s, red);
  __syncthreads();

  const float ps = top_p[b] * s;
  // binary search on positive-float bit space for minimal kept e value
  unsigned lo = 0u, hi = 0x3F800000u;  // (0, 1.0]; pred(lo)=false, pred(hi)=true
  while (hi - lo > 1u) {
    const unsigned mid = (lo + hi) >> 1;
    const float t = __uint_as_float(mid);
    float a = 0.f;
    if (use_e) {
      for (int v = tid; v < V_; v += 256) {
        const float ev = e[v];
        a += (ev > t) ? ev : 0.f;
      }
    } else {
      for (int v = tid; v < V_; v += 256) {
        const float ev = expf(l[v] - m);
        a += (ev > t) ? ev : 0.f;
      }
    }
    a = blockSum256(a, red);
    if (a <= ps) hi = mid; else lo = mid;
  }
  const float c = __uint_as_float(hi);

  // min logit among kept tokens (e >= c)
  float lmin = INFINITY;
  if (use_e) {
    for (int v = tid; v < V_; v += 256)
      if (e[v] >= c) lmin = fminf(lmin, l[v]);
  } else {
    for (int v = tid; v < V_; v += 256)
      if (expf(l[v] - m) >= c) lmin = fminf(lmin, l[v]);
  }
#pragma unroll
  for (int o = 32; o > 0; o >>= 1) lmin = fminf(lmin, __shfl_down(lmin, o));
  const int w = tid >> 6;
  if ((tid & 63) == 0) red[w] = lmin;
  __syncthreads();
  if (tid == 0)
    lmin_out[b] = fminf(fminf(red[0], red[1]), fminf(red[2], red[3]));
}

// ---------------- kernel 3: gumbel argmax, JAX partitionable threefry -------
// bits(j) = fold_xor(threefry2x32((0,42), (j>>32, j&0xffffffff))), j = b*V+v.
// size 4.096e6 < 2^32 so counter hi word is 0.
__global__ __launch_bounds__(256) void sample_kernel(
    const float* __restrict__ L, const float* __restrict__ lmin_arr,
    int* __restrict__ out) {
  __shared__ float rs[4];
  __shared__ int ri[4];
  const int b = blockIdx.x;
  const int tid = threadIdx.x;
  const float* l = L + (size_t)b * V_;
  const float lm = lmin_arr[b];

  float s = -INFINITY;
  int idx = 0x7FFFFFFF;
  for (int v = tid; v < V_; v += 256) {
    const float a = l[v];
    if (a >= lm) {
      unsigned x0 = 0u;
      unsigned x1 = (unsigned)(b * V_ + v);
      threefry2x32_0_42(x0, x1);
      const float sc = a + gumbel_from_bits(x0 ^ x1);
      if (sc > s) { s = sc; idx = v; }   // strict > keeps lowest index on ties
    }
  }
  // wave argmax (tie -> lower index)
#pragma unroll
  for (int o = 32; o > 0; o >>= 1) {
    const float t = __shfl_down(s, o);
    const int j = __shfl_down(idx, o);
    if (t > s || (t == s && j < idx)) { s = t; idx = j; }
  }
  const int w = tid >> 6;
  if ((tid & 63) == 0) { rs[w] = s; ri[w] = idx; }
  __syncthreads();
  if (tid == 0) {
    float bs = rs[0];
    int bi = ri[0];
#pragma unroll
    for (int k = 1; k < 4; k++)
      if (rs[k] > bs || (rs[k] == bs && ri[k] < bi)) { bs = rs[k]; bi = ri[k]; }
    out[b] = bi;
  }
}

extern "C" void kernel_launch(void* const* d_in, const int* in_sizes, int n_in,
                              void* d_out, int out_size, void* d_ws, size_t ws_size,
                              hipStream_t stream) {
  (void)in_sizes; (void)n_in; (void)out_size;
  const float* A = (const float*)d_in[0];     // hidden_states [128,4096]
  const float* W = (const float*)d_in[1];     // embd_weight   [32000,4096]
  const float* temp = (const float*)d_in[2];  // temperature   [128]
  const float* topp = (const float*)d_in[3];  // top_p         [128]
  int* out = (int*)d_out;                     // ids           [128] int32

  char* base = (char*)d_ws;
  const size_t LBytes = (size_t)B_ * V_ * sizeof(float);     // 16.384 MB
  float* L = (float*)base;
  const int use_e = (ws_size >= 2 * LBytes + 1024) ? 1 : 0;  // cache exp values?
  float* E = (float*)(base + (use_e ? LBytes : 0));
  float* lmin_arr = (float*)(base + (use_e ? 2 * LBytes : LBytes));

  gemm_kernel<<<dim3(V_ / 64), dim3(256), 0, stream>>>(A, W, temp, L);
  topp_kernel<<<dim3(B_), dim3(256), 0, stream>>>(L, topp, E, lmin_arr, use_e);
  sample_kernel<<<dim3(B_), dim3(256), 0, stream>>>(L, lmin_arr, out);
}

// Round 3
// 859.128 us; speedup vs baseline: 1.9226x; 1.9226x over previous
//
#include <hip/hip_runtime.h>
#include <math.h>

#define B_ 128
#define D_ 4096
#define V_ 32000

#define BN 64
#define BK 32
#define KSTEPS (D_ / BK)                    // 128
#define ASTEP_BYTES (128 * BK * 2 * 3)      // 24576 B per K-step A image (3 splits)
#define WS_LDS_BYTES (3 * 4 * 4 * 16 * 16)  // 12288 B W fragment image
#define WS_LDS_OFF ASTEP_BYTES

typedef __attribute__((ext_vector_type(8))) short short8;
typedef __attribute__((ext_vector_type(4))) float floatx4;

// ---------------- bf16 helpers (RNE, bit-exact, no header dependency) -------
__device__ __forceinline__ unsigned short bf16_rne(float x) {
  unsigned u = __float_as_uint(x);
  u += 0x7FFFu + ((u >> 16) & 1u);
  return (unsigned short)(u >> 16);
}
__device__ __forceinline__ float bf16_to_f(unsigned short h) {
  return __uint_as_float(((unsigned)h) << 16);
}

// ---------------- threefry2x32, key = (0, 42), JAX partitionable ------------
__device__ __forceinline__ void threefry2x32_0_42(unsigned& x0, unsigned& x1) {
  const unsigned k0 = 0u;
  const unsigned k1 = 42u;
  const unsigned k2 = 0u ^ 42u ^ 0x1BD11BDAu;
  x0 += k0; x1 += k1;
#define TF_R(r) { x0 += x1; x1 = (x1 << (r)) | (x1 >> (32 - (r))); x1 ^= x0; }
#define TF_G0 TF_R(13) TF_R(15) TF_R(26) TF_R(6)
#define TF_G1 TF_R(17) TF_R(29) TF_R(16) TF_R(24)
  TF_G0; x0 += k1; x1 += k2 + 1u;
  TF_G1; x0 += k2; x1 += k0 + 2u;
  TF_G0; x0 += k0; x1 += k1 + 3u;
  TF_G1; x0 += k1; x1 += k2 + 4u;
  TF_G0; x0 += k2; x1 += k0 + 5u;
#undef TF_G1
#undef TF_G0
#undef TF_R
}

__device__ __forceinline__ float gumbel_from_bits(unsigned bits) {
  float f = __uint_as_float((bits >> 9) | 0x3F800000u) - 1.0f;
  float u = fmaxf(f, 1.17549435e-38f);
  return -logf(-logf(u));
}

// ---------------- kernel 0: pre-split A into per-K-step LDS images ----------
// Image layout per step: offset(s,mt,quad,m) = (((s*8+mt)*4+quad)*16+m)*16B,
// holding A_s[mt*16+m][step*32 + quad*8 .. +8] as 8 bf16.
__global__ __launch_bounds__(256) void asplit_kernel(const float* __restrict__ A,
                                                     unsigned short* __restrict__ Asp) {
  const int t = blockIdx.x * 256 + threadIdx.x;  // 0..65535
  const int m_glob = t >> 9;                     // 0..127
  const int koct = t & 511;                      // 0..511 (8-elem groups)
  const int sk = koct >> 2, quad = koct & 3;
  const int mt = m_glob >> 4, ml = m_glob & 15;
  const float* src = A + (size_t)m_glob * D_ + koct * 8;
  short8 h0, h1, h2;
#pragma unroll
  for (int kk = 0; kk < 8; kk++) {
    const float x = src[kk];
    const unsigned short a0 = bf16_rne(x);
    const float r1 = x - bf16_to_f(a0);      // exact (Dekker)
    const unsigned short a1 = bf16_rne(r1);
    const float r2 = r1 - bf16_to_f(a1);     // exact
    const unsigned short a2 = bf16_rne(r2);
    h0[kk] = (short)a0; h1[kk] = (short)a1; h2[kk] = (short)a2;
  }
  unsigned short* dst = Asp + (size_t)sk * (ASTEP_BYTES / 2);
  const int base = ((mt * 4 + quad) * 16 + ml) * 8;     // shorts, s=0
  const int sstride = 8 * 4 * 16 * 8;                   // 4096 shorts per split
  *(short8*)(dst + base) = h0;
  *(short8*)(dst + base + sstride) = h1;
  *(short8*)(dst + base + 2 * sstride) = h2;
}

// ---------------- kernel 1: bf16x6 MFMA GEMM  L[b][v] = (A.W^T)/temp --------
// block tile 128(m) x 64(n), BK=32, 4 waves each 64x32 (4 mt x 2 nt).
__global__ __launch_bounds__(256) void gemm_mfma(const unsigned short* __restrict__ Asp,
                                                 const float* __restrict__ W,
                                                 const float* __restrict__ temp,
                                                 float* __restrict__ L) {
  __shared__ unsigned char lds[ASTEP_BYTES + WS_LDS_BYTES];  // 36864 B
  const int tid = threadIdx.x;
  const int vblock = blockIdx.x * BN;
  const int wave = tid >> 6, lane = tid & 63;
  const int quad = lane >> 4, ml = lane & 15;
  const int wm = wave >> 1, wn = wave & 1;

  // W staging role: thread -> (v row, k octet)
  const int wv = tid >> 2;                 // 0..63
  const int wko = tid & 3;                 // quad of k
  const float* wsrc = W + (size_t)(vblock + wv) * D_ + wko * 8;
  const int wnt = wv >> 4, wvl = wv & 15;
  const int wbase0 = WS_LDS_OFF + (((0 * 4 + wnt) * 4 + wko) * 16 + wvl) * 16;
  const int wsstride = 4 * 4 * 16 * 16;    // 4096 B per split

  floatx4 acc[4][2];
#pragma unroll
  for (int i = 0; i < 4; i++)
#pragma unroll
    for (int j = 0; j < 2; j++) acc[i][j] = (floatx4){0.f, 0.f, 0.f, 0.f};

  for (int st = 0; st < KSTEPS; st++) {
    __syncthreads();
    // --- A: async global -> LDS (pre-split image, contiguous) ---
    const unsigned char* abase = (const unsigned char*)(Asp + (size_t)st * (ASTEP_BYTES / 2));
#pragma unroll
    for (int i = 0; i < 6; i++) {
      const int off = (i * 256 + tid) * 16;
      __builtin_amdgcn_global_load_lds(
          (const __attribute__((address_space(1))) unsigned int*)(abase + off),
          (__attribute__((address_space(3))) unsigned int*)(&lds[off]), 16, 0, 0);
    }
    // --- W: load fp32, split to 3 bf16, write fragment-interleaved LDS ---
    {
      const float* wp = wsrc + st * BK;
      const float4 wa = *(const float4*)(wp);
      const float4 wb = *(const float4*)(wp + 4);
      const float x[8] = {wa.x, wa.y, wa.z, wa.w, wb.x, wb.y, wb.z, wb.w};
      short8 w0, w1, w2;
#pragma unroll
      for (int kk = 0; kk < 8; kk++) {
        const unsigned short b0 = bf16_rne(x[kk]);
        const float r1 = x[kk] - bf16_to_f(b0);
        const unsigned short b1 = bf16_rne(r1);
        const float r2 = r1 - bf16_to_f(b1);
        const unsigned short b2 = bf16_rne(r2);
        w0[kk] = (short)b0; w1[kk] = (short)b1; w2[kk] = (short)b2;
      }
      *(short8*)(&lds[wbase0]) = w0;
      *(short8*)(&lds[wbase0 + wsstride]) = w1;
      *(short8*)(&lds[wbase0 + 2 * wsstride]) = w2;
    }
    __syncthreads();

    // --- fragments ---
    short8 af[3][4];
#pragma unroll
    for (int s = 0; s < 3; s++)
#pragma unroll
      for (int i = 0; i < 4; i++) {
        const int mt = wm * 4 + i;
        af[s][i] = *(const short8*)(&lds[(((s * 8 + mt) * 4 + quad) * 16 + ml) * 16]);
      }
    short8 wf[3][2];
#pragma unroll
    for (int s = 0; s < 3; s++)
#pragma unroll
      for (int j = 0; j < 2; j++) {
        const int nt = wn * 2 + j;
        wf[s][j] = *(const short8*)(&lds[WS_LDS_OFF + (((s * 4 + nt) * 4 + quad) * 16 + ml) * 16]);
      }

    // --- 6-product split MFMA: (0,0) (0,1) (1,0) (1,1) (0,2) (2,0) ---
#pragma unroll
    for (int i = 0; i < 4; i++)
#pragma unroll
      for (int j = 0; j < 2; j++) {
        acc[i][j] = __builtin_amdgcn_mfma_f32_16x16x32_bf16(af[0][i], wf[0][j], acc[i][j], 0, 0, 0);
        acc[i][j] = __builtin_amdgcn_mfma_f32_16x16x32_bf16(af[0][i], wf[1][j], acc[i][j], 0, 0, 0);
        acc[i][j] = __builtin_amdgcn_mfma_f32_16x16x32_bf16(af[1][i], wf[0][j], acc[i][j], 0, 0, 0);
        acc[i][j] = __builtin_amdgcn_mfma_f32_16x16x32_bf16(af[1][i], wf[1][j], acc[i][j], 0, 0, 0);
        acc[i][j] = __builtin_amdgcn_mfma_f32_16x16x32_bf16(af[0][i], wf[2][j], acc[i][j], 0, 0, 0);
        acc[i][j] = __builtin_amdgcn_mfma_f32_16x16x32_bf16(af[2][i], wf[0][j], acc[i][j], 0, 0, 0);
      }
  }

  // --- epilogue: C/D layout col=lane&15, row=(lane>>4)*4+reg ---
#pragma unroll
  for (int i = 0; i < 4; i++)
#pragma unroll
    for (int j = 0; j < 2; j++) {
      const int col = vblock + (wn * 2 + j) * 16 + ml;
#pragma unroll
      for (int r = 0; r < 4; r++) {
        const int row = wm * 64 + i * 16 + quad * 4 + r;
        L[(size_t)row * V_ + col] = acc[i][j][r] / temp[row];
      }
    }
}

// ---------------- fused top-p + gumbel sampler (1 block = 1 row) ------------
#define NBINS 8192
#define SHIFT 17
#define CAP 2048

__device__ __forceinline__ float blockSum1024(float x, float* redf) {
#pragma unroll
  for (int o = 32; o > 0; o >>= 1) x += __shfl_down(x, o);
  const int w = threadIdx.x >> 6;
  __syncthreads();
  if ((threadIdx.x & 63) == 0) redf[w] = x;
  __syncthreads();
  if (threadIdx.x == 0) {
    float t = redf[0];
    for (int k = 1; k < 16; k++) t += redf[k];
    redf[16] = t;
  }
  __syncthreads();
  return redf[16];
}

__device__ __forceinline__ float blockMax1024(float x, float* redf) {
#pragma unroll
  for (int o = 32; o > 0; o >>= 1) x = fmaxf(x, __shfl_down(x, o));
  const int w = threadIdx.x >> 6;
  __syncthreads();
  if ((threadIdx.x & 63) == 0) redf[w] = x;
  __syncthreads();
  if (threadIdx.x == 0) {
    float t = redf[0];
    for (int k = 1; k < 16; k++) t = fmaxf(t, redf[k]);
    redf[16] = t;
  }
  __syncthreads();
  return redf[16];
}

__global__ __launch_bounds__(1024) void sampler_kernel(const float* __restrict__ L,
                                                       const float* __restrict__ top_p,
                                                       int* __restrict__ out) {
  __shared__ float hist[NBINS];     // 32 KB
  __shared__ float listE[CAP];      // 8 KB
  __shared__ int cnt;
  __shared__ float redf[20];
  __shared__ int redi[16];
  const int b = blockIdx.x, tid = threadIdx.x;
  const float* l = L + (size_t)b * V_;

  for (int i = tid; i < NBINS; i += 1024) hist[i] = 0.f;
  if (tid == 0) cnt = 0;
  __syncthreads();

  // pass 1: row max
  float mx = -INFINITY;
  for (int v = tid; v < V_; v += 1024) mx = fmaxf(mx, l[v]);
  mx = blockMax1024(mx, redf);

  // pass 2: S + histogram of e = exp(l - m) on float-bit bins
  float s = 0.f;
  for (int v = tid; v < V_; v += 1024) {
    const float e = expf(l[v] - mx);
    s += e;
    unsigned bin = __float_as_uint(e) >> SHIFT;   // e in (0,1] -> bin <= 8128
    if (bin >= NBINS) bin = NBINS - 1;
    atomicAdd(&hist[bin], e);
  }
  const float S = blockSum1024(s, redf);  // barrier inside also orders hist atomics
  const float ps = top_p[b] * S;

  // binary search: minimal beta with cumAbove(beta) = sum_{bins > beta} <= ps
  int lo = -1, hi = NBINS - 1;
  while (hi - lo > 1) {
    const int mid = (lo + hi) >> 1;
    float a = 0.f;
    for (int i = tid; i < NBINS; i += 1024)
      if (i > mid) a += hist[i];
    a = blockSum1024(a, redf);
    if (a <= ps) hi = mid; else lo = mid;
  }
  const int beta = hi;
  float cumAbove;
  {
    float a = 0.f;
    for (int i = tid; i < NBINS; i += 1024)
      if (i > beta) a += hist[i];
    cumAbove = blockSum1024(a, redf);
  }

  // collect boundary-bin tokens
  for (int v = tid; v < V_; v += 1024) {
    const float e = expf(l[v] - mx);
    unsigned bin = __float_as_uint(e) >> SHIFT;
    if (bin >= NBINS) bin = NBINS - 1;
    if ((int)bin == beta) {
      const int p = atomicAdd(&cnt, 1);
      if (p < CAP) listE[p] = e;
    }
  }
  __syncthreads();
  const int n = cnt;

  // refine cutoff c within bin beta:  kept <=> bits(e) >= c
  long long blo = ((long long)beta << SHIFT) - 1;
  long long bhi = ((long long)(beta + 1)) << SHIFT;
  if (n <= CAP) {
    while (bhi - blo > 1) {
      const long long mid = (blo + bhi) >> 1;
      const float t = __uint_as_float((unsigned)mid);
      float a = 0.f;
      for (int i = tid; i < n; i += 1024) {
        const float e = listE[i];
        if (e > t) a += e;
      }
      a = cumAbove + blockSum1024(a, redf);
      if (a <= ps) bhi = mid; else blo = mid;
    }
  } else {  // rare overflow fallback: full-row predicate
    while (bhi - blo > 1) {
      const long long mid = (blo + bhi) >> 1;
      const float t = __uint_as_float((unsigned)mid);
      float a = 0.f;
      for (int v = tid; v < V_; v += 1024) {
        const float e = expf(l[v] - mx);
        unsigned bin = __float_as_uint(e) >> SHIFT;
        if (bin >= NBINS) bin = NBINS - 1;
        if ((int)bin == beta && e > t) a += e;
      }
      a = cumAbove + blockSum1024(a, redf);
      if (a <= ps) bhi = mid; else blo = mid;
    }
  }
  const unsigned c = (unsigned)bhi;

  // final pass: gumbel-argmax over kept tokens (JAX partitionable threefry)
  float best = -INFINITY;
  int bi = 0x7FFFFFFF;
  for (int v = tid; v < V_; v += 1024) {
    const float lv = l[v];
    const float e = expf(lv - mx);
    if (__float_as_uint(e) >= c) {
      unsigned x0 = 0u, x1 = (unsigned)(b * V_ + v);
      threefry2x32_0_42(x0, x1);
      const float sc = lv + gumbel_from_bits(x0 ^ x1);
      if (sc > best) { best = sc; bi = v; }
    }
  }
#pragma unroll
  for (int o = 32; o > 0; o >>= 1) {
    const float t = __shfl_down(best, o);
    const int j = __shfl_down(bi, o);
    if (t > best || (t == best && j < bi)) { best = t; bi = j; }
  }
  const int w = tid >> 6;
  __syncthreads();
  if ((tid & 63) == 0) { redf[w] = best; redi[w] = bi; }
  __syncthreads();
  if (tid == 0) {
    float bs = redf[0];
    int bidx = redi[0];
    for (int k = 1; k < 16; k++)
      if (redf[k] > bs || (redf[k] == bs && redi[k] < bidx)) { bs = redf[k]; bidx = redi[k]; }
    out[b] = bidx;
  }
}

extern "C" void kernel_launch(void* const* d_in, const int* in_sizes, int n_in,
                              void* d_out, int out_size, void* d_ws, size_t ws_size,
                              hipStream_t stream) {
  (void)in_sizes; (void)n_in; (void)out_size; (void)ws_size;
  const float* A = (const float*)d_in[0];     // hidden_states [128,4096]
  const float* W = (const float*)d_in[1];     // embd_weight   [32000,4096]
  const float* temp = (const float*)d_in[2];  // temperature   [128]
  const float* topp = (const float*)d_in[3];  // top_p         [128]
  int* out = (int*)d_out;                     // ids           [128] int32

  char* base = (char*)d_ws;
  float* L = (float*)base;                                  // 16,384,000 B
  unsigned short* Asp = (unsigned short*)(base + (size_t)B_ * V_ * 4);  // 3,145,728 B

  asplit_kernel<<<dim3(256), dim3(256), 0, stream>>>(A, Asp);
  gemm_mfma<<<dim3(V_ / BN), dim3(256), 0, stream>>>(Asp, W, temp, L);
  sampler_kernel<<<dim3(B_), dim3(1024), 0, stream>>>(L, topp, out);
}